// Round 7
// baseline (1346.549 us; speedup 1.0000x reference)
//
#include <hip/hip_runtime.h>
#include <hip/hip_bf16.h>

#define N_NODES 100000
#define C_DIM   160
#define R_REL   10
#define B_BLK   5
#define CB      32
#define E_EDGES 500000
#define NB      16                 // nodes per block / bucket
#define NBUK    (N_NODES/NB)       // 6250 buckets
#define CAP     320                // slots per bucket (Poisson(80): P(>320) ~ 0)
#define NSF     1762               // fp32 words per node in LDS accum (1760 + 2 pad)

#define CVT_TOTAL  (N_NODES*C_DIM/8)          // 2,000,000
#define CVT_BLKS   ((CVT_TOTAL + 255)/256)    // 7813
#define BZ_BLKS    ((NBUK + 255)/256)         // 25
#define WPK_BLKS   ((2*10*15*64 + 255)/256)   // 75

typedef float  f32x4 __attribute__((ext_vector_type(4)));
typedef float  f32x2 __attribute__((ext_vector_type(2)));
typedef short  s16x8 __attribute__((ext_vector_type(8)));

__device__ __forceinline__ float b2f(unsigned short h){ return __uint_as_float(((unsigned)h)<<16); }
__device__ __forceinline__ unsigned pack2(float a, float b){
  union { __hip_bfloat162 h; unsigned u; } cv;
  cv.h = __float22bfloat162_rn(make_float2(a, b));   // v_cvt_pk_bf16_f32 (RNE)
  return cv.u;
}
__device__ __forceinline__ unsigned short f2b(float f){
  unsigned b = __float_as_uint(f);
  b += 0x7FFFu + ((b>>16)&1u);
  return (unsigned short)(b>>16);
}
__device__ __forceinline__ float4 unpack4(uint2 u){
  return make_float4(b2f((unsigned short)(u.x & 0xFFFF)), b2f((unsigned short)(u.x >> 16)),
                     b2f((unsigned short)(u.y & 0xFFFF)), b2f((unsigned short)(u.y >> 16)));
}

// ---------------- fused prep: fp32->bf16 cvt | bucket-count zero | weight repack ----------------
// wpack layout: wp[((ct*15+ko)*64+lane)*8 + j] = B[k][col], col = ct*16+(lane&15),
// k = ko*32+(lane>>4)*8+j ; k<320: w[r=ko][b=col/32][k%32][col%32] ; k>=320: root[k-320][col]
__global__ __launch_bounds__(256) void k_prep(const float* __restrict__ ne, unsigned short* __restrict__ x0b,
                                              int* __restrict__ bcnt,
                                              const float* __restrict__ w1, const float* __restrict__ root1,
                                              unsigned short* __restrict__ wp1,
                                              const float* __restrict__ w2, const float* __restrict__ root2,
                                              unsigned short* __restrict__ wp2){
  const int b = blockIdx.x;
  const int t = threadIdx.x;
  if (b < CVT_BLKS){
    if (x0b){
      const int i = b*256 + t;
      if (i < CVT_TOTAL){
        const float4* p = (const float4*)ne + (size_t)i*2;
        float4 a = p[0], c = p[1];
        uint4 w;
        w.x = pack2(a.x, a.y); w.y = pack2(a.z, a.w);
        w.z = pack2(c.x, c.y); w.w = pack2(c.z, c.w);
        ((uint4*)x0b)[i] = w;
      }
    }
    return;
  }
  if (b < CVT_BLKS + BZ_BLKS){
    const int i = (b - CVT_BLKS)*256 + t;
    if (i < NBUK) bcnt[i] = 0;
    return;
  }
  {
    const int tid0 = (b - CVT_BLKS - BZ_BLKS)*256 + t;
    if (tid0 >= 2*10*15*64) return;
    const int which = (tid0 >= 9600);
    const int tid = which ? tid0 - 9600 : tid0;
    const float* w    = which ? w2 : w1;
    const float* root = which ? root2 : root1;
    unsigned short* wp = which ? wp2 : wp1;
    const int l  = tid & 63;
    const int ko = (tid>>6) % 15;
    const int ct = tid / (15*64);
    const int col16 = l & 15, kq = l >> 4;
    const int cout = ct*16 + col16;
    const int bb = cout >> 5, d = cout & 31;
    unsigned short* dstp = wp + (size_t)tid*8;
    #pragma unroll
    for (int j=0;j<8;++j){
      float f;
      if (ko < 10){
        int cl = kq*8 + j;
        f = w[((ko*B_BLK + bb)*CB + cl)*CB + d];
      } else {
        int ci = (ko-10)*32 + kq*8 + j;
        f = root[ci*C_DIM + cout];
      }
      dstp[j] = f2b(f);
    }
  }
}

// ---------------- bucket scatter: pked[bucket*CAP + pos] = src | nl<<20 | rel<<24 ----------------
__global__ __launch_bounds__(256) void k_scatter(const int* __restrict__ src, const int* __restrict__ dst,
                                                 const int* __restrict__ et, int* __restrict__ bcnt,
                                                 unsigned* __restrict__ pked){
  int e = blockIdx.x*256 + threadIdx.x;
  if (e < E_EDGES){
    const int d  = dst[e];
    const int bk = d >> 4;
    const int nl = d & 15;
    const int r  = et[e];
    int pos = atomicAdd(&bcnt[bk], 1);
    if (pos < CAP)
      pked[(size_t)bk*CAP + pos] = (unsigned)src[e] | ((unsigned)nl << 20) | ((unsigned)r << 24);
  }
}

// ---------------- fused layer ----------------
// 1024 threads = 16 waves per block of 16 nodes. Phase A: block's edges split evenly
// across waves; per edge: gather 8 ch-quads (uint2/lane), LDS fp32 atomic accumulate
// into swizzled accum (ch 4l+c -> word c*40+l: 2-way bank max), count per (node,rel).
// Normalize in place by rcp(count). Phase B: waves 0..9 one 16-col tile, K=480,
// A-fragments read as 4x ds_read_b64 fp32 + cvt_pk -> bf16.
template<int XF32, int RELU>
__global__ __launch_bounds__(1024, 4) void k_layer(
    const float* __restrict__ xf,            // fp32 features (fallback path)
    const unsigned short* __restrict__ xb,   // bf16 features
    const int* __restrict__ bcnt,            // bucket edge counts
    const unsigned* __restrict__ pked,       // bucket-packed edges
    const unsigned short* __restrict__ wpack,
    const float* __restrict__ bias,
    float* __restrict__ outf,
    unsigned short* __restrict__ outb)
{
  __shared__ float    accumF[NB*NSF];        // 112,768 B
  __shared__ unsigned cnts[NB*R_REL];        // 640 B
  const int tid  = threadIdx.x;
  const int wave = __builtin_amdgcn_readfirstlane(tid >> 6);
  const int lane = tid & 63;
  const int nb   = blockIdx.x * NB;
  const int lc   = (lane < 40) ? lane : (lane - 40);   // channel-quad index
  const bool act = (lane < 40);

  // zero accum + counts
  for (int i = tid; i < NB*NSF; i += 1024) accumF[i] = 0.f;
  for (int i = tid; i < NB*R_REL; i += 1024) cnts[i] = 0u;
  __syncthreads();

  // ---- Phase A: balanced edge-parallel aggregation
  const int bcount = min(bcnt[blockIdx.x], CAP);
  const unsigned* bbase = pked + (size_t)blockIdx.x*CAP;
  const int chunk = (bcount + NB - 1) >> 4;            // per-wave share (<= CAP/16 = 20)
  const int j0 = wave*chunk;
  const int j1 = min(j0 + chunk, bcount);

  unsigned pkl = 0;
  if (j0 + lane < j1) pkl = bbase[j0 + lane];          // one lane-parallel index load

  for (int j = j0; j < j1; j += 8){
    const int g = min(8, j1 - j);
    unsigned pk[8]; uint2 gb[8]; float4 gf[8];
    #pragma unroll
    for (int u=0; u<8; ++u)
      if (u < g) pk[u] = (unsigned)__builtin_amdgcn_readlane((int)pkl, (j - j0) + u);
    #pragma unroll
    for (int u=0; u<8; ++u){
      if (u < g){
        if (XF32) gf[u] = ((const float4*)(xf + (size_t)(pk[u] & 0xFFFFFu)*C_DIM))[lc];
        else      gb[u] = ((const uint2*)(xb + (size_t)(pk[u] & 0xFFFFFu)*C_DIM))[lc];
      }
    }
    #pragma unroll
    for (int u=0; u<8; ++u){
      if (u < g){
        const int nl = (int)((pk[u] >> 20) & 15u);
        const int rl = (int)(pk[u] >> 24);
        float4 gv = XF32 ? gf[u] : unpack4(gb[u]);
        if (act){
          float* bp = &accumF[nl*NSF + rl*C_DIM + lc];   // swizzled: ch 4lc+c -> +c*40
          atomicAdd(bp +   0, gv.x);
          atomicAdd(bp +  40, gv.y);
          atomicAdd(bp +  80, gv.z);
          atomicAdd(bp + 120, gv.w);
        }
        if (lane == 0) atomicAdd(&cnts[nl*R_REL + rl], 1u);
      }
    }
  }

  // root row: x[nb+wave] -> fp32 swizzled at word offset 1600
  {
    const int n = nb + wave;
    float4 v;
    if (XF32) v = ((const float4*)(xf + (size_t)n*C_DIM))[lc];
    else      v = unpack4(((const uint2*)(xb + (size_t)n*C_DIM))[lc]);
    if (act){
      float* rp = &accumF[wave*NSF + 1600 + lc];
      rp[0] = v.x; rp[40] = v.y; rp[80] = v.z; rp[120] = v.w;
    }
  }
  __syncthreads();

  // ---- normalize in place (wave w owns node w)
  #pragma unroll
  for (int r=0; r<R_REL; ++r){
    const unsigned c = cnts[wave*R_REL + r];
    if (c){
      const float s = __builtin_amdgcn_rcpf((float)c);
      for (int i = lane; i < C_DIM; i += 64)
        accumF[wave*NSF + r*C_DIM + i] *= s;
    }
  }
  __syncthreads();

  // ---- Phase B: waves 0..9 -> col-tile ct = wave ; K = 480 (15 MFMA steps)
  if (wave < 10){
    const int ct = wave;
    const int b = ct >> 1;
    const int row16 = lane & 15;   // A row (node) / D col
    const int kq    = lane >> 4;   // k-chunk
    f32x4 c = {0.f, 0.f, 0.f, 0.f};
    #pragma unroll
    for (int ko=0; ko<15; ++ko){
      const int basew = row16*NSF + (ko < 10 ? ko*C_DIM : 1600);
      const int q     = (ko < 10 ? b*8 + kq*2 : (ko-10)*8 + kq*2);
      f32x2 r0 = *(const f32x2*)&accumF[basew +   0 + q];
      f32x2 r1 = *(const f32x2*)&accumF[basew +  40 + q];
      f32x2 r2 = *(const f32x2*)&accumF[basew +  80 + q];
      f32x2 r3 = *(const f32x2*)&accumF[basew + 120 + q];
      union { s16x8 v; unsigned u[4]; } cva;
      cva.u[0] = pack2(r0[0], r1[0]);      // ch 4q+0, 4q+1
      cva.u[1] = pack2(r2[0], r3[0]);      // ch 4q+2, 4q+3
      cva.u[2] = pack2(r0[1], r1[1]);      // ch 4q+4, 4q+5
      cva.u[3] = pack2(r2[1], r3[1]);      // ch 4q+6, 4q+7
      s16x8 bfv = *(const s16x8*)&wpack[(size_t)((ct*15+ko)*64 + lane)*8];
      c = __builtin_amdgcn_mfma_f32_16x16x32_bf16(cva.v, bfv, c, 0, 0, 0);
    }
    const int col = ct*16 + row16;
    const float bv = bias[col];
    #pragma unroll
    for (int q=0;q<4;++q){
      const int nn = nb + kq*4 + q;          // D row = (lane>>4)*4 + q
      float v = c[q] + bv;
      if (RELU) v = fmaxf(v, 0.f);
      if (outf) outf[(size_t)nn*C_DIM + col] = v;
      if (outb) outb[(size_t)nn*C_DIM + col] = f2b(v);
    }
  }
}

// ---------------- ws layout (bytes) ----------------
static constexpr size_t X1_OFF  = 0;                          // bf16 x1: 32,000,000
static constexpr size_t PK_OFF  = 32000000;                   // pked: NBUK*CAP*4 = 8,000,000
static constexpr size_t BC_OFF  = PK_OFF + 8000000;           // bcnt: 25,600
static constexpr size_t WP1_OFF = BC_OFF + 25600;             // 153,600
static constexpr size_t WP2_OFF = WP1_OFF + 153600;           // 153,600
static constexpr size_t X0B_OFF = WP2_OFF + 153600;           // bf16 node_emb: 32,000,000
static constexpr size_t WS_NEED = X0B_OFF + 32000000;         // ~72.3 MB

extern "C" void kernel_launch(void* const* d_in, const int* in_sizes, int n_in,
                              void* d_out, int out_size, void* d_ws, size_t ws_size,
                              hipStream_t stream) {
  const float* node_emb = (const float*)d_in[0];
  const float* w1    = (const float*)d_in[1];
  const float* root1 = (const float*)d_in[2];
  const float* bias1 = (const float*)d_in[3];
  const float* w2    = (const float*)d_in[4];
  const float* root2 = (const float*)d_in[5];
  const float* bias2 = (const float*)d_in[6];
  const int*   ei    = (const int*)d_in[7];   // [2, E]: row0 = src, row1 = dst
  const int*   et    = (const int*)d_in[8];   // [E]

  char* ws = (char*)d_ws;
  unsigned short* x1   = (unsigned short*)(ws + X1_OFF);
  unsigned* pked       = (unsigned*)(ws + PK_OFF);
  int* bcnt            = (int*)(ws + BC_OFF);
  unsigned short* wp1  = (unsigned short*)(ws + WP1_OFF);
  unsigned short* wp2  = (unsigned short*)(ws + WP2_OFF);
  unsigned short* x0b  = (unsigned short*)(ws + X0B_OFF);

  const int* srcI = ei;
  const int* dstI = ei + E_EDGES;
  const bool use_cvt = (ws_size >= WS_NEED);   // host-side constant: identical work every call

  k_prep   <<<CVT_BLKS + BZ_BLKS + WPK_BLKS, 256, 0, stream>>>(
              node_emb, use_cvt ? x0b : nullptr, bcnt, w1, root1, wp1, w2, root2, wp2);
  k_scatter<<<(E_EDGES+255)/256, 256, 0, stream>>>(srcI, dstI, et, bcnt, pked);

  if (use_cvt){
    k_layer<0,1><<<NBUK, 1024, 0, stream>>>(nullptr, x0b, bcnt, pked,
                                            wp1, bias1, nullptr, x1);
  } else {
    k_layer<1,1><<<NBUK, 1024, 0, stream>>>(node_emb, nullptr, bcnt, pked,
                                            wp1, bias1, nullptr, x1);
  }
  k_layer<0,0><<<NBUK, 1024, 0, stream>>>(nullptr, x1, bcnt, pked,
                                          wp2, bias2, (float*)d_out, nullptr);
}

// Round 10
// 373.958 us; speedup vs baseline: 3.6008x; 3.6008x over previous
//
#include <hip/hip_runtime.h>
#include <hip/hip_bf16.h>

#define N_NODES 100000
#define C_DIM   160
#define R_REL   10
#define B_BLK   5
#define CB      32
#define E_EDGES 500000
#define NB      16                 // nodes per block (1 per wave, 16 waves)
#define CAPN    32                 // bucket slots per node (Poisson(5): P(deg>32) ~ 1e-17)
#define ASTRIDE 1768               // ushorts per node row in LDS (221*16B: odd 16B stride)

#define SCT_BLKS   ((E_EDGES + 255)/256)      // 1954
#define CVT_TOTAL  (N_NODES*C_DIM/8)          // 2,000,000
#define CVT_BLKS   ((CVT_TOTAL + 255)/256)    // 7813
#define WPK_BLKS   ((2*10*15*64 + 255)/256)   // 75

typedef float f32x4 __attribute__((ext_vector_type(4)));
typedef short s16x8 __attribute__((ext_vector_type(8)));

__device__ __forceinline__ float b2f(unsigned short h){ return __uint_as_float(((unsigned)h)<<16); }
__device__ __forceinline__ unsigned pack2(float a, float b){
  union { __hip_bfloat162 h; unsigned u; } cv;
  cv.h = __float22bfloat162_rn(make_float2(a, b));   // v_cvt_pk_bf16_f32 (RNE)
  return cv.u;
}
__device__ __forceinline__ unsigned short f2b(float f){
  unsigned b = __float_as_uint(f);
  b += 0x7FFFu + ((b>>16)&1u);
  return (unsigned short)(b>>16);
}
__device__ __forceinline__ float4 unpack4(uint2 u){
  return make_float4(b2f((unsigned short)(u.x & 0xFFFF)), b2f((unsigned short)(u.x >> 16)),
                     b2f((unsigned short)(u.y & 0xFFFF)), b2f((unsigned short)(u.y >> 16)));
}

// ---------------- fused prep: bucket scatter | fp32->bf16 cvt | weight repack ----------------
// (bcnt zeroed by hipMemsetAsync before this launch)
// wpack layout: wp[((ct*15+ko)*64+lane)*8 + j] = B[k][col], col = ct*16+(lane&15),
// k = ko*32+(lane>>4)*8+j ; k<320: w[r=ko][b=col/32][k%32][col%32] ; k>=320: root[k-320][col]
__global__ __launch_bounds__(256) void k_prep(const int* __restrict__ src, const int* __restrict__ dst,
                                              const int* __restrict__ et,
                                              int* __restrict__ bcnt, unsigned* __restrict__ pked,
                                              const float* __restrict__ ne, unsigned short* __restrict__ x0b,
                                              const float* __restrict__ w1, const float* __restrict__ root1,
                                              unsigned short* __restrict__ wp1,
                                              const float* __restrict__ w2, const float* __restrict__ root2,
                                              unsigned short* __restrict__ wp2){
  const int b = blockIdx.x;
  const int t = threadIdx.x;
  if (b < SCT_BLKS){
    const int e = b*256 + t;
    if (e < E_EDGES){
      const int d = dst[e];
      int pos = atomicAdd(&bcnt[d], 1);
      if (pos < CAPN)
        pked[(size_t)d*CAPN + pos] = (unsigned)src[e] | ((unsigned)et[e] << 20);
    }
    return;
  }
  if (b < SCT_BLKS + CVT_BLKS){
    const int i = (b - SCT_BLKS)*256 + t;
    if (i < CVT_TOTAL){
      const float4* p = (const float4*)ne + (size_t)i*2;
      float4 a = p[0], c = p[1];
      uint4 w;
      w.x = pack2(a.x, a.y); w.y = pack2(a.z, a.w);
      w.z = pack2(c.x, c.y); w.w = pack2(c.z, c.w);
      ((uint4*)x0b)[i] = w;
    }
    return;
  }
  {
    const int tid0 = (b - SCT_BLKS - CVT_BLKS)*256 + t;
    if (tid0 >= 2*10*15*64) return;
    const int which = (tid0 >= 9600);
    const int tid = which ? tid0 - 9600 : tid0;
    const float* w    = which ? w2 : w1;
    const float* root = which ? root2 : root1;
    unsigned short* wp = which ? wp2 : wp1;
    const int l  = tid & 63;
    const int ko = (tid>>6) % 15;
    const int ct = tid / (15*64);
    const int col16 = l & 15, kq = l >> 4;
    const int cout = ct*16 + col16;
    const int bb = cout >> 5, d = cout & 31;
    unsigned short* dstp = wp + (size_t)tid*8;
    #pragma unroll
    for (int j=0;j<8;++j){
      float f;
      if (ko < 10){
        int cl = kq*8 + j;
        f = w[((ko*B_BLK + bb)*CB + cl)*CB + d];
      } else {
        int ci = (ko-10)*32 + kq*8 + j;
        f = root[ci*C_DIM + cout];
      }
      dstp[j] = f2b(f);
    }
  }
}

// ---------------- fused layer ----------------
// 1024 threads = 16 waves; wave w aggregates node nb+w.
// Phase A: one lane-parallel bucket load; in-wave ballot sort by rel (rank = prefix +
// mbcnt, ds_permute push); then guarded 8-deep gather batches + flush-on-rel-change
// register accumulate (runs contiguous after sort). Phase B: waves 0..9 one 16-col
// tile each, K=480 (15 MFMA), unchanged verified path.
template<int RELU>
__global__ __launch_bounds__(1024, 8) void k_layer(
    const unsigned short* __restrict__ xb,   // bf16 features
    const int* __restrict__ bcnt,            // per-node edge counts
    const unsigned* __restrict__ pked,       // per-node bucket: src | rel<<20
    const unsigned short* __restrict__ wpack,
    const float* __restrict__ bias,
    float* __restrict__ outf,
    unsigned short* __restrict__ outb)
{
  __shared__ unsigned short A[NB*ASTRIDE];
  const int tid  = threadIdx.x;
  const int wave = __builtin_amdgcn_readfirstlane(tid >> 6);
  const int lane = tid & 63;
  const int nb   = blockIdx.x * NB;
  const int n    = nb + wave;
  const int m    = wave;
  const int lc   = (lane < 40) ? lane : (lane - 40);   // channel-quad index
  const bool act = (lane < 40);

  // pre-zero the 10 mean rows (covers empty relations)
  if (act){
    #pragma unroll
    for (int r=0;r<R_REL;++r)
      *(uint2*)&A[m*ASTRIDE + r*C_DIM + 4*lane] = make_uint2(0u,0u);
  }

  const int cnt = min(bcnt[n], CAPN);

  // ---- load bucket + ballot sort by relation
  unsigned pkl = 0;
  if (lane < cnt) pkl = pked[(size_t)n*CAPN + lane];
  const int myrel = (int)(pkl >> 20);

  unsigned long long bmask[R_REL];
  #pragma unroll
  for (int r=0;r<R_REL;++r) bmask[r] = __ballot(lane < cnt && myrel == r);

  int base = 0;
  unsigned long long msel = bmask[0];
  #pragma unroll
  for (int r=1;r<R_REL;++r){
    const bool ge = (myrel >= r);
    base = ge ? (base + __popcll(bmask[r-1])) : base;
    msel = ge ? bmask[r] : msel;
  }
  const int below = __builtin_amdgcn_mbcnt_hi((unsigned)(msel >> 32),
                    __builtin_amdgcn_mbcnt_lo((unsigned)msel, 0u));
  const int rank = (lane < cnt) ? (base + below) : lane;
  const unsigned spk = (unsigned)__builtin_amdgcn_ds_permute(rank << 2, (int)pkl);

  // ---- guarded 8-deep gather batches, flush-on-rel-change accumulate
  int r_cur = -1, ecnt = 0;
  float4 acc = make_float4(0.f,0.f,0.f,0.f);

  for (int j = 0; j < cnt; j += 8){
    const int g = min(8, cnt - j);              // wave-uniform
    unsigned pk[8]; uint2 gb[8];
    #pragma unroll
    for (int u=0;u<8;++u)
      if (u < g) pk[u] = (unsigned)__builtin_amdgcn_readlane((int)spk, j+u);
    #pragma unroll
    for (int u=0;u<8;++u)
      if (u < g) gb[u] = ((const uint2*)(xb + (size_t)(pk[u] & 0xFFFFFu)*C_DIM))[lc];
    #pragma unroll
    for (int u=0;u<8;++u){
      if (u < g){
        const int rl = (int)(pk[u] >> 20);
        if (rl != r_cur){
          if (r_cur >= 0){
            const float s = __builtin_amdgcn_rcpf((float)ecnt);
            if (act){
              uint2 wv; wv.x = pack2(acc.x*s, acc.y*s); wv.y = pack2(acc.z*s, acc.w*s);
              *(uint2*)&A[m*ASTRIDE + r_cur*C_DIM + 4*lane] = wv;
            }
          }
          r_cur = rl; ecnt = 0; acc = make_float4(0.f,0.f,0.f,0.f);
        }
        float4 gv = unpack4(gb[u]);
        acc.x += gv.x; acc.y += gv.y; acc.z += gv.z; acc.w += gv.w; ecnt++;
      }
    }
  }
  if (r_cur >= 0){
    const float s = __builtin_amdgcn_rcpf((float)ecnt);
    if (act){
      uint2 wv; wv.x = pack2(acc.x*s, acc.y*s); wv.y = pack2(acc.z*s, acc.w*s);
      *(uint2*)&A[m*ASTRIDE + r_cur*C_DIM + 4*lane] = wv;
    }
  }
  { // root row: x[n] at K-offset 1600
    uint2 rw = ((const uint2*)(xb + (size_t)n*C_DIM))[lc];
    if (act) *(uint2*)&A[m*ASTRIDE + 1600 + 4*lane] = rw;
  }
  __syncthreads();

  // ---- Phase B: waves 0..9 -> col-tile ct = wave ; K = 480 (15 MFMA steps)
  if (wave < 10){
    const int ct = wave;
    const int b = ct >> 1;
    const int row16 = lane & 15;   // A row (node) / D col
    const int kq    = lane >> 4;   // k-chunk
    f32x4 c = {0.f, 0.f, 0.f, 0.f};
    #pragma unroll
    for (int ko=0; ko<15; ++ko){
      const int aoff = row16*ASTRIDE + (ko < 10 ? ko*C_DIM + b*CB + kq*8
                                                : 1600 + (ko-10)*CB + kq*8);
      s16x8 af  = *(const s16x8*)&A[aoff];
      s16x8 bfv = *(const s16x8*)&wpack[(size_t)((ct*15+ko)*64 + lane)*8];
      c = __builtin_amdgcn_mfma_f32_16x16x32_bf16(af, bfv, c, 0, 0, 0);
    }
    const int col = ct*16 + row16;
    const float bv = bias[col];
    #pragma unroll
    for (int q=0;q<4;++q){
      const int nn = nb + kq*4 + q;          // D row = (lane>>4)*4 + q
      float v = c[q] + bv;
      if (RELU) v = fmaxf(v, 0.f);
      if (outf) outf[(size_t)nn*C_DIM + col] = v;
      if (outb) outb[(size_t)nn*C_DIM + col] = f2b(v);
    }
  }
}

// ---------------- ws layout (bytes) ----------------
static constexpr size_t X1_OFF  = 0;                          // bf16 x1: 32,000,000
static constexpr size_t PK_OFF  = 32000000;                   // pked: N*CAPN*4 = 12,800,000
static constexpr size_t BC_OFF  = PK_OFF + 12800000;          // bcnt: 400,000
static constexpr size_t WP1_OFF = BC_OFF + 400000;            // 153,600
static constexpr size_t WP2_OFF = WP1_OFF + 153600;           // 153,600
// total ~45.5 MB ; bf16 node_emb (x0b) lives in d_out (64 MB fp32, overwritten only by layer 2)

extern "C" void kernel_launch(void* const* d_in, const int* in_sizes, int n_in,
                              void* d_out, int out_size, void* d_ws, size_t ws_size,
                              hipStream_t stream) {
  const float* node_emb = (const float*)d_in[0];
  const float* w1    = (const float*)d_in[1];
  const float* root1 = (const float*)d_in[2];
  const float* bias1 = (const float*)d_in[3];
  const float* w2    = (const float*)d_in[4];
  const float* root2 = (const float*)d_in[5];
  const float* bias2 = (const float*)d_in[6];
  const int*   ei    = (const int*)d_in[7];   // [2, E]: row0 = src, row1 = dst
  const int*   et    = (const int*)d_in[8];   // [E]

  char* ws = (char*)d_ws;
  unsigned short* x1   = (unsigned short*)(ws + X1_OFF);
  unsigned* pked       = (unsigned*)(ws + PK_OFF);
  int* bcnt            = (int*)(ws + BC_OFF);
  unsigned short* wp1  = (unsigned short*)(ws + WP1_OFF);
  unsigned short* wp2  = (unsigned short*)(ws + WP2_OFF);
  unsigned short* x0b  = (unsigned short*)d_out;   // scratch inside d_out (dead before layer-2 writes)

  const int* srcI = ei;
  const int* dstI = ei + E_EDGES;

  hipMemsetAsync(bcnt, 0, (size_t)N_NODES*sizeof(int), stream);

  k_prep<<<SCT_BLKS + CVT_BLKS + WPK_BLKS, 256, 0, stream>>>(
      srcI, dstI, et, bcnt, pked, node_emb, x0b, w1, root1, wp1, w2, root2, wp2);

  k_layer<1><<<N_NODES/NB, 1024, 0, stream>>>(x0b, bcnt, pked, wp1, bias1, nullptr, x1);
  k_layer<0><<<N_NODES/NB, 1024, 0, stream>>>(x1,  bcnt, pked, wp2, bias2, (float*)d_out, nullptr);
}